// Round 14
// baseline (1004.362 us; speedup 1.0000x reference)
//
#include <hip/hip_runtime.h>
#include <hip/hip_bf16.h>
#include <stdint.h>

#define B_ 4096
#define D_ 64
#define T_ 8
#define H_ 128
#define K_ 32
#define NC_ 10
#define M_ 14

#define P_OFF (B_*NC_*T_)            /* 327680 */
#define N_OFF (P_OFF + B_*T_)        /* 360448 */
#define SX_OFF (N_OFF + B_*T_)       /* 393216 */

#define ROWS 8       /* batch rows per block */
#define THREADS 512

/* ws float offsets for transposed weights: W2[kk][row][4] layouts */
#define WS_WHH 0        /* 32 kk x 384 rows x4 = 49152 */
#define WS_WIH 49152    /* 16 kk x 384 x4 = 24576 */
#define WS_WE  73728    /* 32 kk x 64 x4  = 8192 */
#define WS_WL  81920    /* 8 kk x 128 x4  = 4096 */
#define WS_TOT 86016    /* 344 KB */

typedef float v2f __attribute__((ext_vector_type(2)));

#if __has_builtin(__builtin_elementwise_fma)
#define FMA2(a, b, c) __builtin_elementwise_fma((a), (b), (c))
#else
static __device__ __forceinline__ v2f fma2_(v2f a, v2f b, v2f c) {
  v2f r; r.x = fmaf(a.x, b.x, c.x); r.y = fmaf(a.y, b.y, c.y); return r;
}
#define FMA2(a, b, c) fma2_((a), (b), (c))
#endif

// ---------------- Threefry-2x32 (20 rounds), exactly JAX's ----------------
__device__ __forceinline__ void tf2x32(uint32_t k0, uint32_t k1,
                                       uint32_t c0, uint32_t c1,
                                       uint32_t& o0, uint32_t& o1) {
  uint32_t ks2 = k0 ^ k1 ^ 0x1BD11BDAu;
  uint32_t x0 = c0 + k0, x1 = c1 + k1;
#define TF_R(r) { x0 += x1; x1 = ((x1 << (r)) | (x1 >> (32 - (r)))); x1 ^= x0; }
  TF_R(13) TF_R(15) TF_R(26) TF_R(6)
  x0 += k1; x1 += ks2 + 1u;
  TF_R(17) TF_R(29) TF_R(16) TF_R(24)
  x0 += ks2; x1 += k0 + 2u;
  TF_R(13) TF_R(15) TF_R(26) TF_R(6)
  x0 += k0; x1 += k1 + 3u;
  TF_R(17) TF_R(29) TF_R(16) TF_R(24)
  x0 += k1; x1 += ks2 + 4u;
  TF_R(13) TF_R(15) TF_R(26) TF_R(6)
  x0 += ks2; x1 += k0 + 5u;
#undef TF_R
  o0 = x0; o1 = x1;
}

// XLA ErfInv32 (Giles single-precision polynomial)
__device__ __forceinline__ float erfinv_f(float x) {
  float w = -log1pf(-x * x);
  float p;
  if (w < 5.0f) {
    w -= 2.5f;
    p = 2.81022636e-08f;
    p = fmaf(p, w, 3.43273939e-07f);
    p = fmaf(p, w, -3.5233877e-06f);
    p = fmaf(p, w, -4.39150654e-06f);
    p = fmaf(p, w, 0.00021858087f);
    p = fmaf(p, w, -0.00125372503f);
    p = fmaf(p, w, -0.00417768164f);
    p = fmaf(p, w, 0.246640727f);
    p = fmaf(p, w, 1.50140941f);
  } else {
    w = sqrtf(w) - 3.0f;
    p = -0.000200214257f;
    p = fmaf(p, w, 0.000100950558f);
    p = fmaf(p, w, 0.00134934322f);
    p = fmaf(p, w, -0.00367342844f);
    p = fmaf(p, w, 0.00573950773f);
    p = fmaf(p, w, -0.0076224613f);
    p = fmaf(p, w, 0.00943887047f);
    p = fmaf(p, w, 1.00167406f);
    p = fmaf(p, w, 2.83297682f);
  }
  return p * x;
}

__device__ __forceinline__ float sigmoid_f(float x) { return 1.0f / (1.0f + expf(-x)); }
__device__ __forceinline__ float softplus_f(float x) {
  return (x > 0.0f) ? (x + log1pf(expf(-x))) : log1pf(expf(x));
}

// ---- prologue: transpose weights into ws as W2[kk][row][4] (coalesced reads) ----
__launch_bounds__(256)
__global__ void reorder_kernel(const float* __restrict__ Whh, const float* __restrict__ Wih,
                               const float* __restrict__ We, const float* __restrict__ Wl,
                               float* __restrict__ ws) {
  int i = (int)blockIdx.x * 256 + (int)threadIdx.x;
  if (i < 49152) {                       // Whh: 384x128
    int e = i & 3, ch = i >> 2, j = ch % 384, kk = ch / 384;
    ws[WS_WHH + i] = Whh[j * H_ + kk * 4 + e];
  } else if (i < 73728) {                // Wih: 384x64
    int x2 = i - WS_WIH;
    int e = x2 & 3, ch = x2 >> 2, j = ch % 384, kk = ch / 384;
    ws[i] = Wih[j * D_ + kk * 4 + e];
  } else if (i < 81920) {                // We: 64x128
    int x2 = i - WS_WE;
    int e = x2 & 3, ch = x2 >> 2, j = ch % 64, kk = ch / 64;
    ws[i] = We[j * H_ + kk * 4 + e];
  } else if (i < WS_TOT) {               // Wl: 128x32
    int x2 = i - WS_WL;
    int e = x2 & 3, ch = x2 >> 2, j = ch % 128, kk = ch / 128;
    ws[i] = Wl[j * K_ + kk * 4 + e];
  }
}

// r13 structure (512x512, 8 rows/block, early tick exit) +
// (a) packed row-pair FMA in P1/gi: v2f accumulators hold 2 independent
//     row-chains, each strictly k-ascending -> bit-exact per component.
//     h/x kept in interleaved LDS copies hAi[k][row], xi[d][row].
// (b) pn dedup: idx==63 threads (r=0..7, no y work) compute the halt chain
//     (byte-identical order) -> sh_pn; all threads read after a barrier.
__launch_bounds__(THREADS, 2)
__global__ void vrnn_kernel(const float* __restrict__ x, const float* __restrict__ sx,
                            const float* __restrict__ bih, const float* __restrict__ bhh,
                            const float* __restrict__ be, const float* __restrict__ bl,
                            const float* __restrict__ Wo, const float* __restrict__ bo,
                            const float* __restrict__ Whalt, const float* __restrict__ bhalt,
                            const float* __restrict__ ws, float* __restrict__ out) {
  __shared__ float sh_hA[ROWS][132];     // row-major h (P4/pn/st/y, combine hprev)
  __shared__ float sh_hAi[H_][12];       // interleaved h [k][row] (P1 reads)
  __shared__ float sh_hB[ROWS][132];     // h_gru (combine write; P2 read)
  __shared__ float sh_gh[384 * 9];       // 13.8 KB
  __shared__ float sh_gi[384 * 9];       // 13.8 KB
  __shared__ float sh_z[ROWS][36];
  __shared__ float sh_xi[D_][12];        // interleaved x [d][row] (gi reads)
  __shared__ float sh_pn[ROWS];
  __shared__ uint32_t sh_keys[T_ * M_][2];

  const int tid = (int)threadIdx.x;
  const int r = tid & 7;
  const int idx = tid >> 3;              // 0..63
  const int i0 = idx * 2;
  const int c = idx >> 2;                // y dot (0..15)
  const int q = idx & 3;                 // y quarter
  const int blk = (int)blockIdx.x;
  const int b = blk * ROWS + r;
  const bool isrow = (tid < 384);

  const float* whh2 = ws + WS_WHH;
  const float* wih2 = ws + WS_WIH;
  const float* we2  = ws + WS_WE;
  const float* wl2  = ws + WS_WL;

  if (tid < T_ * M_) {
    uint32_t o0, o1;
    tf2x32(0u, 42u, 0u, (uint32_t)tid, o0, o1);
    sh_keys[tid][0] = o0;
    sh_keys[tid][1] = o1;
  }

  float bhh_j = 0.0f, bih_j = 0.0f;
  if (isrow) { bhh_j = bhh[tid]; bih_j = bih[tid]; }

  // init h carry = sx (both layouts)
#pragma unroll
  for (int e = tid; e < ROWS * H_; e += THREADS) {
    float v = sx[blk * ROWS * H_ + e];
    sh_hA[e >> 7][e & 127] = v;
    sh_hAi[e & 127][e >> 7] = v;
  }
  __syncthreads();

#pragma unroll 1
  for (int t = 0; t < T_; ++t) {
    // ---- stage x_t (interleaved) ----
    { int row = tid >> 6, d = tid & 63;
      sh_xi[d][row] = x[(blk * ROWS + row) * (D_ * T_) + d * T_ + t]; }
    __syncthreads();

    // ---- gi: owner j, 4 packed row-pair chains, coalesced Wih ----
    if (isrow) {
      v2f acc[4];
#pragma unroll
      for (int p = 0; p < 4; ++p) acc[p] = (v2f){bih_j, bih_j};
#pragma unroll 2
      for (int kk = 0; kk < D_ / 4; ++kk) {
        float4 wv = *(const float4*)(wih2 + (kk * 384 + tid) * 4);
#pragma unroll
        for (int ki = 0; ki < 4; ++ki) {
          float wsc = (ki == 0) ? wv.x : (ki == 1) ? wv.y : (ki == 2) ? wv.z : wv.w;
          const v2f* hp = (const v2f*)&sh_xi[kk * 4 + ki][0];
          v2f wb = (v2f){wsc, wsc};
#pragma unroll
          for (int p = 0; p < 4; ++p) acc[p] = FMA2(wb, hp[p], acc[p]);
        }
      }
#pragma unroll
      for (int p = 0; p < 4; ++p) {
        sh_gi[tid * 9 + 2 * p]     = acc[p].x;
        sh_gi[tid * 9 + 2 * p + 1] = acc[p].y;
      }
    }
    // no barrier: P1's trailing barrier orders gi -> combine

    float st0 = 0.0f, st1 = 0.0f, yt = 0.0f;
    float csum = 0.0f, pmprev = 0.0f, rt = 0.0f;
    int nt = -1;

#pragma unroll 1
    for (int m = 0; m < M_; ++m) {
      // ---- P1: gh chains, packed row pairs, coalesced weights ----
      if (isrow) {
        v2f acc[4];
#pragma unroll
        for (int p = 0; p < 4; ++p) acc[p] = (v2f){bhh_j, bhh_j};
#pragma unroll 2
        for (int kk = 0; kk < H_ / 4; ++kk) {
          float4 wv = *(const float4*)(whh2 + (kk * 384 + tid) * 4);
#pragma unroll
          for (int ki = 0; ki < 4; ++ki) {
            float wsc = (ki == 0) ? wv.x : (ki == 1) ? wv.y : (ki == 2) ? wv.z : wv.w;
            const v2f* hp = (const v2f*)&sh_hAi[kk * 4 + ki][0];
            v2f wb = (v2f){wsc, wsc};
#pragma unroll
            for (int p = 0; p < 4; ++p) acc[p] = FMA2(wb, hp[p], acc[p]);
          }
        }
#pragma unroll
        for (int p = 0; p < 4; ++p) {
          sh_gh[tid * 9 + 2 * p]     = acc[p].x;
          sh_gh[tid * 9 + 2 * p + 1] = acc[p].y;
        }
      }
      __syncthreads();

      // ---- combine: 1024 (i,rr) tasks -> sh_hB ----
#pragma unroll
      for (int vv = 0; vv < 2; ++vv) {
        int v = tid + vv * THREADS;
        int rr = v & 7, i = v >> 3;
        float ghr = sh_gh[(0 * H_ + i) * 9 + rr];
        float ghz = sh_gh[(1 * H_ + i) * 9 + rr];
        float ghn = sh_gh[(2 * H_ + i) * 9 + rr];
        float gir = sh_gi[(0 * H_ + i) * 9 + rr];
        float giz = sh_gi[(1 * H_ + i) * 9 + rr];
        float gin = sh_gi[(2 * H_ + i) * 9 + rr];
        float rg = sigmoid_f(gir + ghr);
        float zg = sigmoid_f(giz + ghz);
        float ng = tanhf(fmaf(rg, ghn, gin));
        float hprev = sh_hA[rr][i];
        sh_hB[rr][i] = (1.0f - zg) * ng + zg * hprev;
      }
      __syncthreads();

      // ---- P2: (We-row wr, batch-row rr2) coalesced dot + inline z-draw ----
      {
        int wr = tid & 63, rr2 = tid >> 6;   // 512 tasks exactly
        float acc = be[wr];
#pragma unroll 4
        for (int kk = 0; kk < H_ / 4; ++kk) {
          float4 wv = *(const float4*)(we2 + (kk * 64 + wr) * 4);
          float4 hv = *(const float4*)&sh_hB[rr2][kk * 4];
          acc = fmaf(wv.x, hv.x, acc);
          acc = fmaf(wv.y, hv.y, acc);
          acc = fmaf(wv.z, hv.z, acc);
          acc = fmaf(wv.w, hv.w, acc);
        }
        float accP = __shfl_xor(acc, 32);    // partner wr^32, same rr2
        if (wr < K_) {                       // mu thread: kd=wr, row rr2
          float sg = softplus_f(accP - 5.0f);
          uint32_t key0 = sh_keys[t * M_ + m][0];
          uint32_t key1 = sh_keys[t * M_ + m][1];
          uint32_t e = (uint32_t)(blk * ROWS + rr2) * 32u + (uint32_t)wr;
          uint32_t r0, r1;
          tf2x32(key0, key1, 0u, e, r0, r1);
          uint32_t bits = r0 ^ r1;
          float f = __uint_as_float((bits >> 9) | 0x3f800000u) - 1.0f;
          float u = fmaf(f, 2.0f, -0.99999994f);
          u = fmaxf(-0.99999994f, u);
          float eps = 1.41421356f * erfinv_f(u);
          sh_z[rr2][wr] = fmaf(eps, sg, acc);
        }
      }
      __syncthreads();

      // ---- P3: (Wl-row jl, row-pair rh) coalesced, acc[2] -> hA + hAi ----
      {
        int jl = tid & 127, rh = tid >> 7;   // rh 0..3 -> rows 2rh, 2rh+1
        float a0 = bl[jl], a1 = a0;
#pragma unroll
        for (int kk = 0; kk < K_ / 4; ++kk) {
          float4 wv = *(const float4*)(wl2 + (kk * 128 + jl) * 4);
          float4 z0 = *(const float4*)&sh_z[rh * 2][kk * 4];
          float4 z1 = *(const float4*)&sh_z[rh * 2 + 1][kk * 4];
          a0 = fmaf(wv.x, z0.x, a0); a1 = fmaf(wv.x, z1.x, a1);
          a0 = fmaf(wv.y, z0.y, a0); a1 = fmaf(wv.y, z1.y, a1);
          a0 = fmaf(wv.z, z0.z, a0); a1 = fmaf(wv.z, z1.z, a1);
          a0 = fmaf(wv.w, z0.w, a0); a1 = fmaf(wv.w, z1.w, a1);
        }
        float t0 = tanhf(a0), t1 = tanhf(a1);
        sh_hA[rh * 2][jl] = t0;
        sh_hA[rh * 2 + 1][jl] = t1;
        *(v2f*)&sh_hAi[jl][rh * 2] = (v2f){t0, t1};
      }
      __syncthreads();

      // ---- P4a: pn chain by idx==63 (8 threads) || y quarter-dots ----
      if (idx == 63) {
        float pa = bhalt[0];
#pragma unroll 2
        for (int kk = 0; kk < H_ / 4; ++kk) {
          float4 hv = *(const float4*)&sh_hA[r][kk * 4];
          float4 av = *(const float4*)(Whalt + kk * 4);   // uniform -> s_load
          pa = fmaf(av.x, hv.x, pa); pa = fmaf(av.y, hv.y, pa);
          pa = fmaf(av.z, hv.z, pa); pa = fmaf(av.w, hv.w, pa);
        }
        sh_pn[r] = sigmoid_f(pa);
      }
      float yv = 0.0f;
      if (c < NC_) {
        float yq = (q == 0) ? bo[c] : 0.0f;
        const float* wo = Wo + c * H_ + q * 32;
#pragma unroll
        for (int kk = 0; kk < 8; ++kk) {
          float4 hv = *(const float4*)&sh_hA[r][q * 32 + kk * 4];
          float4 ov = *(const float4*)(wo + kk * 4);
          yq = fmaf(ov.x, hv.x, yq); yq = fmaf(ov.y, hv.y, yq);
          yq = fmaf(ov.z, hv.z, yq); yq = fmaf(ov.w, hv.w, yq);
        }
        yq += __shfl_xor(yq, 8);
        yq += __shfl_xor(yq, 16);
        yv = yq;
      }
      __syncthreads();

      // ---- P4b: halting update (pn broadcast from LDS) ----
      {
        float pn = sh_pn[r];
        csum += pn;
        float pm = (m == M_ - 1) ? 1.0f : fminf(1.0f, csum);
        if (nt < 0 && (csum >= 1.0f || m == M_ - 1)) {
          nt = m;
          rt = (m == 0) ? 0.0f : (1.0f - pmprev);
        }
        float ph = pm - pmprev;
        pmprev = pm;
        st0 = fmaf(ph, sh_hA[r][i0], st0);
        st1 = fmaf(ph, sh_hA[r][i0 + 1], st1);
        yt = fmaf(ph, yv, yt);
      }

      // ---- early tick exit: all rows halted -> remaining ticks are exact 0s ----
      if (__syncthreads_and(csum >= 1.0f)) break;
      // (this barrier also orders P4's hA reads before next P1/P3 writes)
    }  // ticks

    // ---- step end ----
    __syncthreads();   // all P4 hA reads done (full-M path)
    sh_hA[r][i0] = st0;
    sh_hA[r][i0 + 1] = st1;
    sh_hAi[i0][r] = st0;
    sh_hAi[i0 + 1][r] = st1;
    if (c < NC_ && q == 0) out[b * (NC_ * T_) + c * T_ + t] = yt;
    if (idx == 40) {
      out[P_OFF + b * T_ + t] = (float)nt + rt;
      out[N_OFF + b * T_ + t] = (float)nt;
    }
    if (t == T_ - 1) {
      out[SX_OFF + b * H_ + i0] = st0;
      out[SX_OFF + b * H_ + i0 + 1] = st1;
    }
    __syncthreads();
  }  // steps
}

extern "C" void kernel_launch(void* const* d_in, const int* in_sizes, int n_in,
                              void* d_out, int out_size, void* d_ws, size_t ws_size,
                              hipStream_t stream) {
  (void)in_sizes; (void)n_in; (void)out_size; (void)ws_size;
  const float* x     = (const float*)d_in[0];
  const float* sx    = (const float*)d_in[1];
  const float* Wih   = (const float*)d_in[2];
  const float* Whh   = (const float*)d_in[3];
  const float* bih   = (const float*)d_in[4];
  const float* bhh   = (const float*)d_in[5];
  const float* We    = (const float*)d_in[6];
  const float* be    = (const float*)d_in[7];
  const float* Wl    = (const float*)d_in[8];
  const float* bl    = (const float*)d_in[9];
  const float* Wo    = (const float*)d_in[10];
  const float* bo    = (const float*)d_in[11];
  const float* Whalt = (const float*)d_in[12];
  const float* bhalt = (const float*)d_in[13];
  float* ws  = (float*)d_ws;
  float* out = (float*)d_out;

  reorder_kernel<<<dim3((WS_TOT + 255) / 256), dim3(256), 0, stream>>>(Whh, Wih, We, Wl, ws);
  vrnn_kernel<<<dim3(B_ / ROWS), dim3(THREADS), 0, stream>>>(x, sx, bih, bhh, be, bl,
                                                             Wo, bo, Whalt, bhalt, ws, out);
}

// Round 15
// 640.121 us; speedup vs baseline: 1.5690x; 1.5690x over previous
//
#include <hip/hip_runtime.h>
#include <hip/hip_bf16.h>
#include <stdint.h>

#define B_ 4096
#define D_ 64
#define T_ 8
#define H_ 128
#define K_ 32
#define NC_ 10
#define M_ 14

#define P_OFF (B_*NC_*T_)            /* 327680 */
#define N_OFF (P_OFF + B_*T_)        /* 360448 */
#define SX_OFF (N_OFF + B_*T_)       /* 393216 */

#define ROWS 8       /* batch rows per block */
#define THREADS 512

/* ws float offsets for transposed weights: W2[kk][row][4] layouts */
#define WS_WHH 0        /* 32 kk x 384 rows x4 = 49152 */
#define WS_WIH 49152    /* 16 kk x 384 x4 = 24576 */
#define WS_WE  73728    /* 32 kk x 64 x4  = 8192 */
#define WS_WL  81920    /* 8 kk x 128 x4  = 4096 */
#define WS_TOT 86016    /* 344 KB */

// ---------------- Threefry-2x32 (20 rounds), exactly JAX's ----------------
__device__ __forceinline__ void tf2x32(uint32_t k0, uint32_t k1,
                                       uint32_t c0, uint32_t c1,
                                       uint32_t& o0, uint32_t& o1) {
  uint32_t ks2 = k0 ^ k1 ^ 0x1BD11BDAu;
  uint32_t x0 = c0 + k0, x1 = c1 + k1;
#define TF_R(r) { x0 += x1; x1 = ((x1 << (r)) | (x1 >> (32 - (r)))); x1 ^= x0; }
  TF_R(13) TF_R(15) TF_R(26) TF_R(6)
  x0 += k1; x1 += ks2 + 1u;
  TF_R(17) TF_R(29) TF_R(16) TF_R(24)
  x0 += ks2; x1 += k0 + 2u;
  TF_R(13) TF_R(15) TF_R(26) TF_R(6)
  x0 += k0; x1 += k1 + 3u;
  TF_R(17) TF_R(29) TF_R(16) TF_R(24)
  x0 += k1; x1 += ks2 + 4u;
  TF_R(13) TF_R(15) TF_R(26) TF_R(6)
  x0 += ks2; x1 += k0 + 5u;
#undef TF_R
  o0 = x0; o1 = x1;
}

// XLA ErfInv32 (Giles single-precision polynomial)
__device__ __forceinline__ float erfinv_f(float x) {
  float w = -log1pf(-x * x);
  float p;
  if (w < 5.0f) {
    w -= 2.5f;
    p = 2.81022636e-08f;
    p = fmaf(p, w, 3.43273939e-07f);
    p = fmaf(p, w, -3.5233877e-06f);
    p = fmaf(p, w, -4.39150654e-06f);
    p = fmaf(p, w, 0.00021858087f);
    p = fmaf(p, w, -0.00125372503f);
    p = fmaf(p, w, -0.00417768164f);
    p = fmaf(p, w, 0.246640727f);
    p = fmaf(p, w, 1.50140941f);
  } else {
    w = sqrtf(w) - 3.0f;
    p = -0.000200214257f;
    p = fmaf(p, w, 0.000100950558f);
    p = fmaf(p, w, 0.00134934322f);
    p = fmaf(p, w, -0.00367342844f);
    p = fmaf(p, w, 0.00573950773f);
    p = fmaf(p, w, -0.0076224613f);
    p = fmaf(p, w, 0.00943887047f);
    p = fmaf(p, w, 1.00167406f);
    p = fmaf(p, w, 2.83297682f);
  }
  return p * x;
}

__device__ __forceinline__ float sigmoid_f(float x) { return 1.0f / (1.0f + expf(-x)); }
__device__ __forceinline__ float softplus_f(float x) {
  return (x > 0.0f) ? (x + log1pf(expf(-x))) : log1pf(expf(x));
}

// ---- prologue: transpose weights into ws as W2[kk][row][4] (coalesced reads) ----
__launch_bounds__(256)
__global__ void reorder_kernel(const float* __restrict__ Whh, const float* __restrict__ Wih,
                               const float* __restrict__ We, const float* __restrict__ Wl,
                               float* __restrict__ ws) {
  int i = (int)blockIdx.x * 256 + (int)threadIdx.x;
  if (i < 49152) {                       // Whh: 384x128
    int e = i & 3, ch = i >> 2, j = ch % 384, kk = ch / 384;
    ws[WS_WHH + i] = Whh[j * H_ + kk * 4 + e];
  } else if (i < 73728) {                // Wih: 384x64
    int x2 = i - WS_WIH;
    int e = x2 & 3, ch = x2 >> 2, j = ch % 384, kk = ch / 384;
    ws[i] = Wih[j * D_ + kk * 4 + e];
  } else if (i < 81920) {                // We: 64x128
    int x2 = i - WS_WE;
    int e = x2 & 3, ch = x2 >> 2, j = ch % 64, kk = ch / 64;
    ws[i] = We[j * H_ + kk * 4 + e];
  } else if (i < WS_TOT) {               // Wl: 128x32
    int x2 = i - WS_WL;
    int e = x2 & 3, ch = x2 >> 2, j = ch % 128, kk = ch / 128;
    ws[i] = Wl[j * K_ + kk * 4 + e];
  }
}

// r13 structure (512x512, 8 rows/block, coalesced owner-thread weights,
// early tick exit) + pn dedup ONLY: the identical-per-row 128-FMA halt
// chain is computed by the 8 idle threads idx==63 (byte-identical order
// -> bit-exact) into sh_pn[r]; one barrier; everyone reads the broadcast.
// (r14's packed-FMA LDS restructure regressed 658->1004 us and is reverted.)
__launch_bounds__(THREADS, 2)
__global__ void vrnn_kernel(const float* __restrict__ x, const float* __restrict__ sx,
                            const float* __restrict__ bih, const float* __restrict__ bhh,
                            const float* __restrict__ be, const float* __restrict__ bl,
                            const float* __restrict__ Wo, const float* __restrict__ bo,
                            const float* __restrict__ Whalt, const float* __restrict__ bhalt,
                            const float* __restrict__ ws, float* __restrict__ out) {
  __shared__ float sh_hA[ROWS][132];     // h carry / hb
  __shared__ float sh_hB[ROWS][132];     // h_gru
  __shared__ float sh_gh[384 * 9];       // 13.8 KB
  __shared__ float sh_gi[384 * 9];       // 13.8 KB
  __shared__ float sh_z[ROWS][36];
  __shared__ float sh_x[ROWS][68];
  __shared__ float sh_pn[ROWS];
  __shared__ uint32_t sh_keys[T_ * M_][2];

  const int tid = (int)threadIdx.x;
  const int r = tid & 7;
  const int idx = tid >> 3;              // 0..63
  const int i0 = idx * 2;
  const int c = idx >> 2;                // y dot (0..15)
  const int q = idx & 3;                 // y quarter
  const int blk = (int)blockIdx.x;
  const int b = blk * ROWS + r;
  const bool isrow = (tid < 384);

  const float* whh2 = ws + WS_WHH;
  const float* wih2 = ws + WS_WIH;
  const float* we2  = ws + WS_WE;
  const float* wl2  = ws + WS_WL;

  if (tid < T_ * M_) {
    uint32_t o0, o1;
    tf2x32(0u, 42u, 0u, (uint32_t)tid, o0, o1);
    sh_keys[tid][0] = o0;
    sh_keys[tid][1] = o1;
  }

  float bhh_j = 0.0f, bih_j = 0.0f;
  if (isrow) { bhh_j = bhh[tid]; bih_j = bih[tid]; }

  // init h carry = sx
#pragma unroll
  for (int e = tid; e < ROWS * H_; e += THREADS)
    sh_hA[e >> 7][e & 127] = sx[blk * ROWS * H_ + e];
  __syncthreads();

#pragma unroll 1
  for (int t = 0; t < T_; ++t) {
    // ---- stage x_t (512 elems) ----
    { int row = tid >> 6, d = tid & 63;
      sh_x[row][d] = x[(blk * ROWS + row) * (D_ * T_) + d * T_ + t]; }
    __syncthreads();

    // ---- gi: owner j, 8 k-ascending chains, coalesced Wih ----
    if (isrow) {
      float acc[8];
#pragma unroll
      for (int rr = 0; rr < 8; ++rr) acc[rr] = bih_j;
#pragma unroll 2
      for (int kk = 0; kk < D_ / 4; ++kk) {
        float4 wv = *(const float4*)(wih2 + (kk * 384 + tid) * 4);
#pragma unroll
        for (int rr = 0; rr < 8; ++rr) {
          float4 hv = *(const float4*)&sh_x[rr][kk * 4];
          acc[rr] = fmaf(wv.x, hv.x, acc[rr]);
          acc[rr] = fmaf(wv.y, hv.y, acc[rr]);
          acc[rr] = fmaf(wv.z, hv.z, acc[rr]);
          acc[rr] = fmaf(wv.w, hv.w, acc[rr]);
        }
      }
#pragma unroll
      for (int rr = 0; rr < 8; ++rr) sh_gi[tid * 9 + rr] = acc[rr];
    }
    // no barrier: P1's trailing barrier orders gi -> combine

    float st0 = 0.0f, st1 = 0.0f, yt = 0.0f;
    float csum = 0.0f, pmprev = 0.0f, rt = 0.0f;
    int nt = -1;

#pragma unroll 1
    for (int m = 0; m < M_; ++m) {
      // ---- P1: gh chains, coalesced weights, 8-row reuse ----
      if (isrow) {
        float acc[8];
#pragma unroll
        for (int rr = 0; rr < 8; ++rr) acc[rr] = bhh_j;
#pragma unroll 2
        for (int kk = 0; kk < H_ / 4; ++kk) {
          float4 wv = *(const float4*)(whh2 + (kk * 384 + tid) * 4);
#pragma unroll
          for (int rr = 0; rr < 8; ++rr) {
            float4 hv = *(const float4*)&sh_hA[rr][kk * 4];
            acc[rr] = fmaf(wv.x, hv.x, acc[rr]);
            acc[rr] = fmaf(wv.y, hv.y, acc[rr]);
            acc[rr] = fmaf(wv.z, hv.z, acc[rr]);
            acc[rr] = fmaf(wv.w, hv.w, acc[rr]);
          }
        }
#pragma unroll
        for (int rr = 0; rr < 8; ++rr) sh_gh[tid * 9 + rr] = acc[rr];
      }
      __syncthreads();

      // ---- combine: 1024 (i,rr) tasks -> sh_hB ----
#pragma unroll
      for (int vv = 0; vv < 2; ++vv) {
        int v = tid + vv * THREADS;
        int rr = v & 7, i = v >> 3;
        float ghr = sh_gh[(0 * H_ + i) * 9 + rr];
        float ghz = sh_gh[(1 * H_ + i) * 9 + rr];
        float ghn = sh_gh[(2 * H_ + i) * 9 + rr];
        float gir = sh_gi[(0 * H_ + i) * 9 + rr];
        float giz = sh_gi[(1 * H_ + i) * 9 + rr];
        float gin = sh_gi[(2 * H_ + i) * 9 + rr];
        float rg = sigmoid_f(gir + ghr);
        float zg = sigmoid_f(giz + ghz);
        float ng = tanhf(fmaf(rg, ghn, gin));
        float hprev = sh_hA[rr][i];
        sh_hB[rr][i] = (1.0f - zg) * ng + zg * hprev;
      }
      __syncthreads();

      // ---- P2: (We-row wr, batch-row rr2) coalesced dot + inline z-draw ----
      {
        int wr = tid & 63, rr2 = tid >> 6;   // 512 tasks exactly
        float acc = be[wr];
#pragma unroll 4
        for (int kk = 0; kk < H_ / 4; ++kk) {
          float4 wv = *(const float4*)(we2 + (kk * 64 + wr) * 4);
          float4 hv = *(const float4*)&sh_hB[rr2][kk * 4];
          acc = fmaf(wv.x, hv.x, acc);
          acc = fmaf(wv.y, hv.y, acc);
          acc = fmaf(wv.z, hv.z, acc);
          acc = fmaf(wv.w, hv.w, acc);
        }
        float accP = __shfl_xor(acc, 32);    // partner wr^32, same rr2
        if (wr < K_) {                       // mu thread: kd=wr, row rr2
          float sg = softplus_f(accP - 5.0f);
          uint32_t key0 = sh_keys[t * M_ + m][0];
          uint32_t key1 = sh_keys[t * M_ + m][1];
          uint32_t e = (uint32_t)(blk * ROWS + rr2) * 32u + (uint32_t)wr;
          uint32_t r0, r1;
          tf2x32(key0, key1, 0u, e, r0, r1);
          uint32_t bits = r0 ^ r1;
          float f = __uint_as_float((bits >> 9) | 0x3f800000u) - 1.0f;
          float u = fmaf(f, 2.0f, -0.99999994f);
          u = fmaxf(-0.99999994f, u);
          float eps = 1.41421356f * erfinv_f(u);
          sh_z[rr2][wr] = fmaf(eps, sg, acc);
        }
      }
      __syncthreads();

      // ---- P3: (Wl-row jl, row-pair rh) coalesced, acc[2] -> sh_hA ----
      {
        int jl = tid & 127, rh = tid >> 7;   // rh 0..3 -> rows 2rh, 2rh+1
        float a0 = bl[jl], a1 = a0;
#pragma unroll
        for (int kk = 0; kk < K_ / 4; ++kk) {
          float4 wv = *(const float4*)(wl2 + (kk * 128 + jl) * 4);
          float4 z0 = *(const float4*)&sh_z[rh * 2][kk * 4];
          float4 z1 = *(const float4*)&sh_z[rh * 2 + 1][kk * 4];
          a0 = fmaf(wv.x, z0.x, a0); a1 = fmaf(wv.x, z1.x, a1);
          a0 = fmaf(wv.y, z0.y, a0); a1 = fmaf(wv.y, z1.y, a1);
          a0 = fmaf(wv.z, z0.z, a0); a1 = fmaf(wv.z, z1.z, a1);
          a0 = fmaf(wv.w, z0.w, a0); a1 = fmaf(wv.w, z1.w, a1);
        }
        sh_hA[rh * 2][jl] = tanhf(a0);
        sh_hA[rh * 2 + 1][jl] = tanhf(a1);
      }
      __syncthreads();

      // ---- P4a: pn chain by idx==63 (8 idle-in-y threads) || y quarter-dots ----
      if (idx == 63) {
        float pa = bhalt[0];
#pragma unroll 2
        for (int kk = 0; kk < H_ / 4; ++kk) {
          float4 hv = *(const float4*)&sh_hA[r][kk * 4];
          float4 av = *(const float4*)(Whalt + kk * 4);   // uniform -> s_load
          pa = fmaf(av.x, hv.x, pa); pa = fmaf(av.y, hv.y, pa);
          pa = fmaf(av.z, hv.z, pa); pa = fmaf(av.w, hv.w, pa);
        }
        sh_pn[r] = sigmoid_f(pa);
      }
      float yv = 0.0f;
      if (c < NC_) {
        float yq = (q == 0) ? bo[c] : 0.0f;
        const float* wo = Wo + c * H_ + q * 32;
#pragma unroll
        for (int kk = 0; kk < 8; ++kk) {
          float4 hv = *(const float4*)&sh_hA[r][q * 32 + kk * 4];
          float4 ov = *(const float4*)(wo + kk * 4);
          yq = fmaf(ov.x, hv.x, yq); yq = fmaf(ov.y, hv.y, yq);
          yq = fmaf(ov.z, hv.z, yq); yq = fmaf(ov.w, hv.w, yq);
        }
        yq += __shfl_xor(yq, 8);
        yq += __shfl_xor(yq, 16);
        yv = yq;
      }
      __syncthreads();   // sh_pn ready

      // ---- P4b: halting update (pn broadcast from LDS) ----
      {
        float pn = sh_pn[r];
        csum += pn;
        float pm = (m == M_ - 1) ? 1.0f : fminf(1.0f, csum);
        if (nt < 0 && (csum >= 1.0f || m == M_ - 1)) {
          nt = m;
          rt = (m == 0) ? 0.0f : (1.0f - pmprev);
        }
        float ph = pm - pmprev;
        pmprev = pm;
        st0 = fmaf(ph, sh_hA[r][i0], st0);
        st1 = fmaf(ph, sh_hA[r][i0 + 1], st1);
        yt = fmaf(ph, yv, yt);
      }

      // ---- early tick exit: all rows halted -> remaining ticks are exact 0s ----
      if (__syncthreads_and(csum >= 1.0f)) break;
      // (this barrier also orders P4's hA reads before next P1's gh writes)
    }  // ticks

    // ---- step end ----
    __syncthreads();   // all P4 hA reads done (full-M path)
    sh_hA[r][i0] = st0;
    sh_hA[r][i0 + 1] = st1;
    if (c < NC_ && q == 0) out[b * (NC_ * T_) + c * T_ + t] = yt;
    if (idx == 40) {
      out[P_OFF + b * T_ + t] = (float)nt + rt;
      out[N_OFF + b * T_ + t] = (float)nt;
    }
    if (t == T_ - 1) {
      out[SX_OFF + b * H_ + i0] = st0;
      out[SX_OFF + b * H_ + i0 + 1] = st1;
    }
    __syncthreads();
  }  // steps
}

extern "C" void kernel_launch(void* const* d_in, const int* in_sizes, int n_in,
                              void* d_out, int out_size, void* d_ws, size_t ws_size,
                              hipStream_t stream) {
  (void)in_sizes; (void)n_in; (void)out_size; (void)ws_size;
  const float* x     = (const float*)d_in[0];
  const float* sx    = (const float*)d_in[1];
  const float* Wih   = (const float*)d_in[2];
  const float* Whh   = (const float*)d_in[3];
  const float* bih   = (const float*)d_in[4];
  const float* bhh   = (const float*)d_in[5];
  const float* We    = (const float*)d_in[6];
  const float* be    = (const float*)d_in[7];
  const float* Wl    = (const float*)d_in[8];
  const float* bl    = (const float*)d_in[9];
  const float* Wo    = (const float*)d_in[10];
  const float* bo    = (const float*)d_in[11];
  const float* Whalt = (const float*)d_in[12];
  const float* bhalt = (const float*)d_in[13];
  float* ws  = (float*)d_ws;
  float* out = (float*)d_out;

  reorder_kernel<<<dim3((WS_TOT + 255) / 256), dim3(256), 0, stream>>>(Whh, Wih, We, Wl, ws);
  vrnn_kernel<<<dim3(B_ / ROWS), dim3(THREADS), 0, stream>>>(x, sx, bih, bhh, be, bl,
                                                             Wo, bo, Whalt, bhalt, ws, out);
}